// Round 1
// 771.170 us; speedup vs baseline: 1.0276x; 1.0276x over previous
//
#include <hip/hip_runtime.h>
#include <hip/hip_fp16.h>
#include <math.h>

#define C 16
#define FIN 128

// ---------------- GEMM x@W1 (100k x 128 x 16) + fused a_s/a_d ----------------
__global__ __launch_bounds__(256) void k_gemm1(
    const float* __restrict__ x, const float* __restrict__ W,
    const float* __restrict__ asw, const float* __restrict__ adw,
    float* __restrict__ h, float* __restrict__ a_s, float* __restrict__ a_d, int n) {
  __shared__ float xs[64 * 129];
  __shared__ float Ws[FIN * C];
  __shared__ float pAs[4][64], pAd[4][64];
  int t = threadIdx.x;
  int node0 = blockIdx.x * 64;
  for (int i = t; i < FIN * C; i += 256) Ws[i] = W[i];
  for (int i = t; i < 64 * FIN; i += 256) {
    int r = i >> 7, c = i & 127;
    int node = node0 + r;
    xs[r * 129 + c] = (node < n) ? x[(size_t)node * FIN + c] : 0.f;
  }
  __syncthreads();
  int nn = t & 63, cg = (t >> 6) * 4, grp = t >> 6;
  float a0 = 0.f, a1 = 0.f, a2 = 0.f, a3 = 0.f;
  const float* xr = &xs[nn * 129];
  #pragma unroll 8
  for (int k = 0; k < FIN; ++k) {
    float xv = xr[k];
    const float* wr = &Ws[k * C + cg];
    a0 += xv * wr[0]; a1 += xv * wr[1]; a2 += xv * wr[2]; a3 += xv * wr[3];
  }
  int node = node0 + nn;
  if (node < n) {
    float4* outp = (float4*)&h[(size_t)node * C + cg];
    *outp = make_float4(a0, a1, a2, a3);
  }
  pAs[grp][nn] = a0 * asw[cg] + a1 * asw[cg + 1] + a2 * asw[cg + 2] + a3 * asw[cg + 3];
  pAd[grp][nn] = a0 * adw[cg] + a1 * adw[cg + 1] + a2 * adw[cg + 2] + a3 * adw[cg + 3];
  __syncthreads();
  if (t < 64 && node0 + t < n) {
    a_s[node0 + t] = pAs[0][t] + pAs[1][t] + pAs[2][t] + pAs[3][t];
    a_d[node0 + t] = pAd[0][t] + pAd[1][t] + pAd[2][t] + pAd[3][t];
  }
}

// ---------------- CSR build ----------------
__global__ __launch_bounds__(256) void k_hist_rank(
    const int* __restrict__ dst, int* __restrict__ counts,
    int* __restrict__ rank, int ne) {
  int e = blockIdx.x * 256 + threadIdx.x;
  if (e < ne) rank[e] = atomicAdd(&counts[dst[e]], 1);
}

__global__ __launch_bounds__(512) void k_scan1(const int* __restrict__ counts,
                                               int* __restrict__ bsum, int n) {
  __shared__ int sd[512];
  int i = blockIdx.x * 512 + threadIdx.x;
  sd[threadIdx.x] = (i < n) ? counts[i] : 0;
  __syncthreads();
  for (int s = 256; s > 0; s >>= 1) {
    if (threadIdx.x < s) sd[threadIdx.x] += sd[threadIdx.x + s];
    __syncthreads();
  }
  if (threadIdx.x == 0) bsum[blockIdx.x] = sd[0];
}

__global__ __launch_bounds__(512) void k_scan2(int* __restrict__ bsum,
                                               int* __restrict__ offs,
                                               int nblk, int n) {
  __shared__ int sd[512];
  int t = threadIdx.x;
  int v = (t < nblk) ? bsum[t] : 0;
  sd[t] = v;
  __syncthreads();
  for (int off = 1; off < 512; off <<= 1) {
    int x = (t >= off) ? sd[t - off] : 0;
    __syncthreads();
    sd[t] += x;
    __syncthreads();
  }
  if (t < nblk) bsum[t] = sd[t] - v;
  if (t == nblk - 1) offs[n] = sd[t];
}

__global__ __launch_bounds__(512) void k_scan3(const int* __restrict__ counts,
                                               const int* __restrict__ bsum,
                                               int* __restrict__ offs, int n) {
  __shared__ int sd[512];
  int t = threadIdx.x;
  int i = blockIdx.x * 512 + t;
  int v = (i < n) ? counts[i] : 0;
  sd[t] = v;
  __syncthreads();
  for (int off = 1; off < 512; off <<= 1) {
    int x = (t >= off) ? sd[t - off] : 0;
    __syncthreads();
    sd[t] += x;
    __syncthreads();
  }
  if (i < n) offs[i] = bsum[blockIdx.x] + sd[t] - v;
}

__global__ __launch_bounds__(256) void k_scatter(
    const int* __restrict__ src, const int* __restrict__ dst,
    const float2* __restrict__ ea, const int* __restrict__ offs,
    const int* __restrict__ rank, uint2* __restrict__ bucket, int ne) {
  int e = blockIdx.x * 256 + threadIdx.x;
  if (e >= ne) return;
  int d = dst[e];
  float2 a = ea[e];
  __half2 hh = __floats2half2_rn(a.x, a.y);
  unsigned int hb;
  memcpy(&hb, &hh, 4);
  bucket[offs[d] + rank[e]] = make_uint2((unsigned int)src[e], hb);
}

// ---------------- per-node gather: 16 lanes per node ----------------
// 4 quads of 4 lanes; each quad owns edge slots, lane f=l&3 loads float4 #f of
// h[src] (one 64B line per edge per instruction). a_s[src] is reconstructed
// in-register from the gathered row (dot with att_s + 2 quad shuffles), so the
// per-edge a_s gather is eliminated entirely.
__global__ __launch_bounds__(256) void k_gather(
    const uint2* __restrict__ bucket, const int* __restrict__ offs,
    const float* __restrict__ a_s, const float* __restrict__ a_d,
    const float* __restrict__ h,
    const float* __restrict__ We, const float* __restrict__ aew,
    const float* __restrict__ asw, const float* __restrict__ bias,
    float* __restrict__ outv, float* __restrict__ bnsum, float* __restrict__ bnsq,
    int do_bn, int n) {
  __shared__ float sbn[32];
  int t = threadIdx.x;
  if (t < 32) sbn[t] = 0.f;
  __syncthreads();

  int node = blockIdx.x * 16 + (t >> 4);
  int l = t & 15;
  int q = l >> 2, f = l & 3;

  float we0 = 0.f, we1 = 0.f;
  #pragma unroll
  for (int c = 0; c < C; ++c) { we0 += We[c] * aew[c]; we1 += We[C + c] * aew[c]; }
  float4 aswf = ((const float4*)asw)[f];

  float4 acc = make_float4(0.f, 0.f, 0.f, 0.f);
  float den = 0.f, lax = 0.f, lay = 0.f;
  int o0 = 0, o1 = 0;
  float adi = 0.f, asi = 0.f;
  if (node < n) {
    o0 = offs[node]; o1 = offs[node + 1];
    adi = a_d[node]; asi = a_s[node];
    for (int e = o0 + 2 * q; e < o1; e += 8) {
      int e1 = e + 1;
      bool p1 = e1 < o1;
      uint2 r0 = bucket[e];
      uint2 r1 = p1 ? bucket[e1] : make_uint2(0u, 0u);
      float4 h0 = ((const float4*)(h + (size_t)r0.x * C))[f];
      float4 h1 = p1 ? ((const float4*)(h + (size_t)r1.x * C))[f]
                     : make_float4(0.f, 0.f, 0.f, 0.f);
      __half2 hh0, hh1;
      memcpy(&hh0, &r0.y, 4);
      memcpy(&hh1, &r1.y, 4);
      float2 ea0 = __half22float2(hh0);
      float2 ea1 = __half22float2(hh1);
      // a_s[src] = dot(h_row, att_s): 4 terms/lane + quad reduce
      float d0 = h0.x * aswf.x + h0.y * aswf.y + h0.z * aswf.z + h0.w * aswf.w;
      float d1 = h1.x * aswf.x + h1.y * aswf.y + h1.z * aswf.z + h1.w * aswf.w;
      d0 += __shfl_xor(d0, 1); d0 += __shfl_xor(d0, 2);
      d1 += __shfl_xor(d1, 1); d1 += __shfl_xor(d1, 2);
      float lg0 = d0 + adi + ea0.x * we0 + ea0.y * we1;
      float lg1 = d1 + adi + ea1.x * we0 + ea1.y * we1;
      lg0 = lg0 > 0.f ? lg0 : 0.2f * lg0;
      lg1 = lg1 > 0.f ? lg1 : 0.2f * lg1;
      float ex0 = __expf(lg0);
      float ex1 = p1 ? __expf(lg1) : 0.f;
      den += ex0 + ex1;
      lax += ea0.x + ea1.x;   // ea1 == 0 when !p1
      lay += ea0.y + ea1.y;
      acc.x += ex0 * h0.x + ex1 * h1.x;
      acc.y += ex0 * h0.y + ex1 * h1.y;
      acc.z += ex0 * h0.z + ex1 * h1.z;
      acc.w += ex0 * h0.w + ex1 * h1.w;
    }
  }
  // reduce across the 4 quads (lane-id bits 2,3); within-quad values are
  // already identical for den/lax/lay, so no over-count scaling needed.
  acc.x += __shfl_xor(acc.x, 4); acc.y += __shfl_xor(acc.y, 4);
  acc.z += __shfl_xor(acc.z, 4); acc.w += __shfl_xor(acc.w, 4);
  den += __shfl_xor(den, 4); lax += __shfl_xor(lax, 4); lay += __shfl_xor(lay, 4);
  acc.x += __shfl_xor(acc.x, 8); acc.y += __shfl_xor(acc.y, 8);
  acc.z += __shfl_xor(acc.z, 8); acc.w += __shfl_xor(acc.w, 8);
  den += __shfl_xor(den, 8); lax += __shfl_xor(lax, 8); lay += __shfl_xor(lay, 8);

  float4 v = make_float4(0.f, 0.f, 0.f, 0.f);
  if (node < n) {
    float dgc = fmaxf((float)(o1 - o0), 1.f);
    float lg = asi + adi + (lax * we0 + lay * we1) / dgc;
    lg = lg > 0.f ? lg : 0.2f * lg;
    float exs = __expf(lg);
    float4 hi = ((const float4*)(h + (size_t)node * C))[f];
    float4 b4 = ((const float4*)bias)[f];
    float dent = den + exs;
    float inv = 1.f / dent;
    v.x = fmaxf((acc.x + exs * hi.x) * inv + b4.x, 0.f);
    v.y = fmaxf((acc.y + exs * hi.y) * inv + b4.y, 0.f);
    v.z = fmaxf((acc.z + exs * hi.z) * inv + b4.z, 0.f);
    v.w = fmaxf((acc.w + exs * hi.w) * inv + b4.w, 0.f);
    if (q == 0) ((float4*)(outv + (size_t)node * C))[f] = v;
  }

  if (do_bn) {
    float4 s4 = (node < n && q == 0) ? v : make_float4(0.f, 0.f, 0.f, 0.f);
    float4 q4 = make_float4(s4.x * s4.x, s4.y * s4.y, s4.z * s4.z, s4.w * s4.w);
    // fold the 4 node-groups of this wave together (lanes l, l+16, l+32, l+48)
    s4.x += __shfl_down(s4.x, 32); s4.y += __shfl_down(s4.y, 32);
    s4.z += __shfl_down(s4.z, 32); s4.w += __shfl_down(s4.w, 32);
    q4.x += __shfl_down(q4.x, 32); q4.y += __shfl_down(q4.y, 32);
    q4.z += __shfl_down(q4.z, 32); q4.w += __shfl_down(q4.w, 32);
    s4.x += __shfl_down(s4.x, 16); s4.y += __shfl_down(s4.y, 16);
    s4.z += __shfl_down(s4.z, 16); s4.w += __shfl_down(s4.w, 16);
    q4.x += __shfl_down(q4.x, 16); q4.y += __shfl_down(q4.y, 16);
    q4.z += __shfl_down(q4.z, 16); q4.w += __shfl_down(q4.w, 16);
    if ((t & 63) < 4) {
      int c0 = f * 4;
      atomicAdd(&sbn[c0 + 0], s4.x); atomicAdd(&sbn[c0 + 1], s4.y);
      atomicAdd(&sbn[c0 + 2], s4.z); atomicAdd(&sbn[c0 + 3], s4.w);
      atomicAdd(&sbn[16 + c0 + 0], q4.x); atomicAdd(&sbn[16 + c0 + 1], q4.y);
      atomicAdd(&sbn[16 + c0 + 2], q4.z); atomicAdd(&sbn[16 + c0 + 3], q4.w);
    }
    __syncthreads();
    if (t < 16) atomicAdd(&bnsum[t], sbn[t]);
    else if (t < 32) atomicAdd(&bnsq[t - 16], sbn[t]);
  }
}

__global__ void k_bnp(const float* __restrict__ bnsum, const float* __restrict__ bnsq,
                      const float* __restrict__ g, const float* __restrict__ bb,
                      float* __restrict__ scale, float* __restrict__ shift, float invn) {
  int c = threadIdx.x;
  if (c >= C) return;
  float mean = bnsum[c] * invn;
  float var = bnsq[c] * invn - mean * mean;
  float s = g[c] * rsqrtf(var + 1e-5f);
  scale[c] = s; shift[c] = bb[c] - mean * s;
}

// ---------------- BN + 16x16 matmul + a_s/a_d for layer 2 ----------------
__global__ __launch_bounds__(256) void k_node2(
    const float* __restrict__ outv, const float* __restrict__ scale,
    const float* __restrict__ shift, const float* __restrict__ W2,
    const float* __restrict__ asw, const float* __restrict__ adw,
    float* __restrict__ h, float* __restrict__ a_s, float* __restrict__ a_d, int n) {
  __shared__ float w2s[C * C];
  if (threadIdx.x < C * C) w2s[threadIdx.x] = W2[threadIdx.x];
  __syncthreads();
  int i = blockIdx.x * 256 + threadIdx.x;
  if (i >= n) return;
  float hn[C];
  #pragma unroll
  for (int c = 0; c < C; ++c) hn[c] = outv[(size_t)i * C + c] * scale[c] + shift[c];
  float h2[C];
  #pragma unroll
  for (int j = 0; j < C; ++j) {
    float acc = 0.f;
    #pragma unroll
    for (int c = 0; c < C; ++c) acc += hn[c] * w2s[c * C + j];
    h2[j] = acc;
  }
  float hs = 0.f, hd = 0.f;
  #pragma unroll
  for (int j = 0; j < C; ++j) { hs += h2[j] * asw[j]; hd += h2[j] * adw[j]; }
  a_s[i] = hs; a_d[i] = hd;
  float4* hp = (float4*)&h[(size_t)i * C];
  hp[0] = make_float4(h2[0], h2[1], h2[2], h2[3]);
  hp[1] = make_float4(h2[4], h2[5], h2[6], h2[7]);
  hp[2] = make_float4(h2[8], h2[9], h2[10], h2[11]);
  hp[3] = make_float4(h2[12], h2[13], h2[14], h2[15]);
}

// ---------------- graph segment offsets ----------------
__global__ void k_gstart(const int* __restrict__ batch, int* __restrict__ gs,
                         int n, int B_) {
  int g = blockIdx.x * blockDim.x + threadIdx.x;
  if (g > B_) return;
  if (g == B_) { gs[B_] = n; return; }
  int lo = 0, hi = n;
  while (lo < hi) { int mid = (lo + hi) >> 1; if (batch[mid] < g) lo = mid + 1; else hi = mid; }
  gs[g] = lo;
}

__global__ __launch_bounds__(256) void k_xe(
    const float* __restrict__ outv, const int* __restrict__ gs,
    float* __restrict__ xe, int B_) {
  int wave = blockIdx.x * 4 + (threadIdx.x >> 6);
  if (wave >= B_) return;
  int lane = threadIdx.x & 63;
  int c = lane & 15, sub = lane >> 4;
  int base = gs[wave], end = gs[wave + 1];
  float s = 0.f;
  for (int n0 = base + sub; n0 < end; n0 += 4) s += outv[(size_t)n0 * C + c];
  s += __shfl_down(s, 32);
  s += __shfl_down(s, 16);
  if (lane < 16) xe[(size_t)wave * C + c] = s / fmaxf((float)(end - base), 1.f);
}

// ---------------- D2RL tail: BN/MLP stages only (z3 out, no spills) ----------------
__global__ __launch_bounds__(512) void k_tail_z3(
    const float* __restrict__ xe_in,
    const float* __restrict__ gL1, const float* __restrict__ bL1,
    const float* __restrict__ Wl1, const float* __restrict__ bl1,
    const float* __restrict__ gL2, const float* __restrict__ bL2,
    const float* __restrict__ Wl2, const float* __restrict__ bl2,
    const float* __restrict__ gL3, const float* __restrict__ bL3,
    const float* __restrict__ Wl3, const float* __restrict__ bl3,
    float* __restrict__ z3buf, int B_) {
  __shared__ float ssum[2 * C], ssq[2 * C], sc[2 * C], sh[2 * C];
  int t = threadIdx.x;
  float invB = 1.f / (float)B_;
  float xe[C];
  #pragma unroll
  for (int c = 0; c < C; ++c) xe[c] = xe_in[(size_t)t * C + c];

  if (t < 2 * C) { ssum[t] = 0.f; ssq[t] = 0.f; }
  __syncthreads();
  #pragma unroll
  for (int c = 0; c < C; ++c) {
    float s = xe[c], q = xe[c] * xe[c];
    for (int o = 32; o > 0; o >>= 1) { s += __shfl_down(s, o); q += __shfl_down(q, o); }
    if ((t & 63) == 0) { atomicAdd(&ssum[c], s); atomicAdd(&ssq[c], q); }
  }
  __syncthreads();
  if (t < C) {
    float mean = ssum[t] * invB, var = ssq[t] * invB - mean * mean;
    float s = gL1[t] * rsqrtf(var + 1e-5f);
    sc[t] = s; sh[t] = bL1[t] - mean * s;
  }
  __syncthreads();
  float z[C];
  #pragma unroll
  for (int j = 0; j < C; ++j) {
    float acc = bl1[j];
    #pragma unroll
    for (int c = 0; c < C; ++c) acc += (xe[c] * sc[c] + sh[c]) * Wl1[c * C + j];
    z[j] = fmaxf(acc, 0.f);
  }
  __syncthreads();

  if (t < 2 * C) { ssum[t] = 0.f; ssq[t] = 0.f; }
  __syncthreads();
  #pragma unroll
  for (int c = 0; c < C; ++c) {
    float s = z[c], q = z[c] * z[c];
    for (int o = 32; o > 0; o >>= 1) { s += __shfl_down(s, o); q += __shfl_down(q, o); }
    if ((t & 63) == 0) { atomicAdd(&ssum[c], s); atomicAdd(&ssq[c], q); }
    float s2 = xe[c], q2 = xe[c] * xe[c];
    for (int o = 32; o > 0; o >>= 1) { s2 += __shfl_down(s2, o); q2 += __shfl_down(q2, o); }
    if ((t & 63) == 0) { atomicAdd(&ssum[C + c], s2); atomicAdd(&ssq[C + c], q2); }
  }
  __syncthreads();
  if (t < 2 * C) {
    float mean = ssum[t] * invB, var = ssq[t] * invB - mean * mean;
    float s = gL2[t] * rsqrtf(var + 1e-5f);
    sc[t] = s; sh[t] = bL2[t] - mean * s;
  }
  __syncthreads();
  float z2[C];
  #pragma unroll
  for (int j = 0; j < C; ++j) {
    float acc = bl2[j];
    #pragma unroll
    for (int c = 0; c < C; ++c) acc += (z[c] * sc[c] + sh[c]) * Wl2[c * C + j];
    #pragma unroll
    for (int c = 0; c < C; ++c) acc += (xe[c] * sc[C + c] + sh[C + c]) * Wl2[(C + c) * C + j];
    z2[j] = fmaxf(acc, 0.f);
  }
  __syncthreads();

  if (t < 2 * C) { ssum[t] = 0.f; ssq[t] = 0.f; }
  __syncthreads();
  #pragma unroll
  for (int c = 0; c < C; ++c) {
    float s = z2[c], q = z2[c] * z2[c];
    for (int o = 32; o > 0; o >>= 1) { s += __shfl_down(s, o); q += __shfl_down(q, o); }
    if ((t & 63) == 0) { atomicAdd(&ssum[c], s); atomicAdd(&ssq[c], q); }
    float s2 = xe[c], q2 = xe[c] * xe[c];
    for (int o = 32; o > 0; o >>= 1) { s2 += __shfl_down(s2, o); q2 += __shfl_down(q2, o); }
    if ((t & 63) == 0) { atomicAdd(&ssum[C + c], s2); atomicAdd(&ssq[C + c], q2); }
  }
  __syncthreads();
  if (t < 2 * C) {
    float mean = ssum[t] * invB, var = ssq[t] * invB - mean * mean;
    float s = gL3[t] * rsqrtf(var + 1e-5f);
    sc[t] = s; sh[t] = bL3[t] - mean * s;
  }
  __syncthreads();
  #pragma unroll
  for (int j = 0; j < C; ++j) {
    float acc = bl3[j];
    #pragma unroll
    for (int c = 0; c < C; ++c) acc += (z2[c] * sc[c] + sh[c]) * Wl3[c * C + j];
    #pragma unroll
    for (int c = 0; c < C; ++c) acc += (xe[c] * sc[C + c] + sh[C + c]) * Wl3[(C + c) * C + j];
    z3buf[(size_t)t * C + j] = fmaxf(acc, 0.f);
  }
}

// ---------------- heads: one wave per graph, lane j = output j ----------------
__global__ __launch_bounds__(256) void k_heads(
    const float* __restrict__ z3buf,
    const float* __restrict__ Wx, const float* __restrict__ bx,
    const float* __restrict__ Wy, const float* __restrict__ by,
    const float* __restrict__ Wr, const float* __restrict__ br,
    float* __restrict__ out, int B_) {
  int wv = blockIdx.x * 4 + (threadIdx.x >> 6);
  if (wv >= B_) return;
  int lane = threadIdx.x & 63;
  float z[C];
  #pragma unroll
  for (int c = 0; c < C; ++c) z[c] = z3buf[(size_t)wv * C + c];

  // x head
  float ax = bx[lane];
  #pragma unroll
  for (int c = 0; c < C; ++c) ax += z[c] * Wx[c * 64 + lane];
  float m = ax;
  #pragma unroll
  for (int o = 32; o > 0; o >>= 1) m = fmaxf(m, __shfl_xor(m, o));
  float e = __expf(ax - m);
  float s = e;
  #pragma unroll
  for (int o = 32; o > 0; o >>= 1) s += __shfl_xor(s, o);
  out[(size_t)wv * 64 + lane] = e / s;

  // y head
  float ay = by[lane];
  #pragma unroll
  for (int c = 0; c < C; ++c) ay += z[c] * Wy[c * 64 + lane];
  m = ay;
  #pragma unroll
  for (int o = 32; o > 0; o >>= 1) m = fmaxf(m, __shfl_xor(m, o));
  e = __expf(ay - m);
  s = e;
  #pragma unroll
  for (int o = 32; o > 0; o >>= 1) s += __shfl_xor(s, o);
  out[(size_t)B_ * 64 + (size_t)wv * 64 + lane] = e / s;

  // rot head (4 outputs in lanes 0..3; shfl_xor 1,2 stays within the quad)
  if (lane < 4) {
    float ar = br[lane];
    #pragma unroll
    for (int c = 0; c < C; ++c) ar += z[c] * Wr[c * 4 + lane];
    float mr = ar;
    mr = fmaxf(mr, __shfl_xor(mr, 1));
    mr = fmaxf(mr, __shfl_xor(mr, 2));
    float er = __expf(ar - mr);
    float sr = er;
    sr += __shfl_xor(sr, 1);
    sr += __shfl_xor(sr, 2);
    out[(size_t)B_ * 128 + (size_t)wv * 4 + lane] = er / sr;
  }
}

extern "C" void kernel_launch(void* const* d_in, const int* in_sizes, int n_in,
                              void* d_out, int out_size, void* d_ws, size_t ws_size,
                              hipStream_t stream) {
  const float* x     = (const float*)d_in[0];
  const int*   eidx  = (const int*)d_in[1];
  const float* eattr = (const float*)d_in[2];
  const int*   batch = (const int*)d_in[3];
  const float* W1  = (const float*)d_in[4];
  const float* We1 = (const float*)d_in[5];
  const float* as1 = (const float*)d_in[6];
  const float* ad1 = (const float*)d_in[7];
  const float* ae1 = (const float*)d_in[8];
  const float* b1  = (const float*)d_in[9];
  const float* g1  = (const float*)d_in[10];
  const float* bb1 = (const float*)d_in[11];
  const float* W2  = (const float*)d_in[12];
  const float* We2 = (const float*)d_in[13];
  const float* as2 = (const float*)d_in[14];
  const float* ad2 = (const float*)d_in[15];
  const float* ae2 = (const float*)d_in[16];
  const float* b2  = (const float*)d_in[17];
  const float* gL1 = (const float*)d_in[18];
  const float* bL1 = (const float*)d_in[19];
  const float* Wl1 = (const float*)d_in[20];
  const float* bl1 = (const float*)d_in[21];
  const float* gL2 = (const float*)d_in[22];
  const float* bL2 = (const float*)d_in[23];
  const float* Wl2 = (const float*)d_in[24];
  const float* bl2 = (const float*)d_in[25];
  const float* gL3 = (const float*)d_in[26];
  const float* bL3 = (const float*)d_in[27];
  const float* Wl3 = (const float*)d_in[28];
  const float* bl3 = (const float*)d_in[29];
  const float* Wx  = (const float*)d_in[30];
  const float* bx  = (const float*)d_in[31];
  const float* Wy  = (const float*)d_in[32];
  const float* by  = (const float*)d_in[33];
  const float* Wr  = (const float*)d_in[34];
  const float* br  = (const float*)d_in[35];

  int N = in_sizes[3];
  int E = in_sizes[2] / 2;
  int B = out_size / 132;
  int nblk = (N + 511) / 512;

  char* w = (char*)d_ws;
  size_t o = 0;
  auto alloc = [&](size_t bytes) { char* p = w + o; o += (bytes + 15) & ~15ull; return p; };
  uint2* bucket  = (uint2*)alloc((size_t)E * 8);
  int*   rank    = (int*)alloc((size_t)E * 4);
  float* h       = (float*)alloc((size_t)N * C * 4);
  float* outv    = (float*)alloc((size_t)N * C * 4);
  float* a_s     = (float*)alloc((size_t)N * 4);
  float* a_d     = (float*)alloc((size_t)N * 4);
  int*   counts  = (int*)alloc((size_t)N * 4);
  int*   offs    = (int*)alloc((size_t)(N + 4) * 4);
  int*   bsum    = (int*)alloc((size_t)(nblk + 4) * 4);
  float* bn      = (float*)alloc(64 * 4);
  float* xe      = (float*)alloc((size_t)B * C * 4);
  int*   gs      = (int*)alloc((size_t)(B + 4) * 4);
  float* z3buf   = (float*)alloc((size_t)B * C * 4);

  const int* src = eidx;
  const int* dst = eidx + E;
  int ebl = (E + 255) / 256;
  int nbl = (N + 255) / 256;

  hipMemsetAsync(counts, 0, (size_t)N * 4, stream);
  hipMemsetAsync(bn, 0, 32 * 4, stream);

  k_gemm1<<<(N + 63) / 64, 256, 0, stream>>>(x, W1, as1, ad1, h, a_s, a_d, N);
  k_hist_rank<<<ebl, 256, 0, stream>>>(dst, counts, rank, E);
  k_scan1<<<nblk, 512, 0, stream>>>(counts, bsum, N);
  k_scan2<<<1, 512, 0, stream>>>(bsum, offs, nblk, N);
  k_scan3<<<nblk, 512, 0, stream>>>(counts, bsum, offs, N);
  k_scatter<<<ebl, 256, 0, stream>>>(src, dst, (const float2*)eattr, offs, rank, bucket, E);
  k_gather<<<(N + 15) / 16, 256, 0, stream>>>(bucket, offs, a_s, a_d, h, We1, ae1, as1, b1,
                                              outv, bn, bn + 16, 1, N);
  k_bnp<<<1, 64, 0, stream>>>(bn, bn + 16, g1, bb1, bn + 32, bn + 48, 1.f / (float)N);
  k_node2<<<nbl, 256, 0, stream>>>(outv, bn + 32, bn + 48, W2, as2, ad2, h, a_s, a_d, N);
  k_gather<<<(N + 15) / 16, 256, 0, stream>>>(bucket, offs, a_s, a_d, h, We2, ae2, as2, b2,
                                              outv, bn, bn + 16, 0, N);
  k_gstart<<<(B + 1 + 255) / 256, 256, 0, stream>>>(batch, gs, N, B);
  k_xe<<<(B + 3) / 4, 256, 0, stream>>>(outv, gs, xe, B);
  k_tail_z3<<<1, B, 0, stream>>>(xe, gL1, bL1, Wl1, bl1, gL2, bL2, Wl2, bl2,
                                 gL3, bL3, Wl3, bl3, z3buf, B);
  k_heads<<<(B + 3) / 4, 256, 0, stream>>>(z3buf, Wx, bx, Wy, by, Wr, br,
                                           (float*)d_out, B);
}